// Round 19
// baseline (145.646 us; speedup 1.0000x reference)
//
#include <hip/hip_runtime.h>
#include <hip/hip_bf16.h>

#define N_    8
#define H_    32
#define W_    32
#define C_    768
#define NH_   12
#define HD_   64
#define B_    96      // N_*NH_
#define HW_   1024
#define C3_   2304
#define SCALE_ 0.125f
#define LOG2E_ 1.4426950408889634f

typedef __attribute__((ext_vector_type(4))) float f32x4;
typedef __attribute__((ext_vector_type(16))) float f32x16;
typedef __attribute__((ext_vector_type(8))) short s16x8;
typedef __attribute__((ext_vector_type(2))) int i32x2;
typedef __attribute__((ext_vector_type(2))) unsigned int u32x2;
typedef __attribute__((ext_vector_type(4))) unsigned int u32x4;
typedef unsigned short u16;
typedef unsigned int u32;

__device__ inline u16 f2b(float x) {
    __hip_bfloat16 h = __float2bfloat16(x);
    return *reinterpret_cast<u16*>(&h);
}
__device__ inline float b2f(u16 x) {
    u32 u = ((u32)x) << 16;
    return *reinterpret_cast<float*>(&u);
}
__device__ __forceinline__ u32 cvtpk(float a, float b) {
    u32 r;
    asm("v_cvt_pk_bf16_f32 %0, %1, %2" : "=v"(r) : "v"(a), "v"(b));
    return r;
}

__device__ __forceinline__ void gld_lds16(const void* g, void* l) {
    __builtin_amdgcn_global_load_lds(
        (const __attribute__((address_space(1))) u32*)g,
        (__attribute__((address_space(3))) u32*)l, 16, 0, 0);
}

// ---------------------------------------------------------------------------
// convert fp32 -> bf16 (vectorized, grid-stride)
// ---------------------------------------------------------------------------
__global__ __launch_bounds__(256) void cvt_bf16(const float* __restrict__ in,
                                                u16* __restrict__ out, int n4) {
    for (int i = blockIdx.x * blockDim.x + threadIdx.x; i < n4; i += gridDim.x * blockDim.x) {
        float4 v = ((const float4*)in)[i];
        ushort4 o;
        o.x = f2b(v.x); o.y = f2b(v.y); o.z = f2b(v.z); o.w = f2b(v.w);
        ((ushort4*)out)[i] = o;
    }
}

// ---------------------------------------------------------------------------
// transpose-convert: in [K][N] fp32 -> out [N][K] bf16, 64x64 tiles
// ---------------------------------------------------------------------------
__global__ __launch_bounds__(256) void tcvt_bf16(const float* __restrict__ in,
                                                 u16* __restrict__ out, int K, int N) {
    __shared__ u16 tile[64][72];
    const int t = threadIdx.x;
    const int k0 = blockIdx.y * 64, n0 = blockIdx.x * 64;
    const int r = t >> 2, c4 = (t & 3) * 16;
    #pragma unroll
    for (int u = 0; u < 4; ++u) {
        float4 v = *(const float4*)(in + (size_t)(k0 + r) * N + n0 + c4 + u * 4);
        tile[c4 + u*4 + 0][r] = f2b(v.x);
        tile[c4 + u*4 + 1][r] = f2b(v.y);
        tile[c4 + u*4 + 2][r] = f2b(v.z);
        tile[c4 + u*4 + 3][r] = f2b(v.w);
    }
    __syncthreads();
    #pragma unroll
    for (int u = 0; u < 2; ++u) {
        s16x8 v;
        #pragma unroll
        for (int e = 0; e < 8; ++e) v[e] = (short)tile[r][c4 + u*8 + e];
        *(s16x8*)(out + (size_t)(n0 + r) * K + k0 + c4 + u*8) = v;
    }
}

// ---------------------------------------------------------------------------
// GEMM core, 3-DEEP pipeline, 32x32x16 MFMA + T2 both-sides XOR swizzle.
// 128x128 tile, BK=32, 4 waves 2x2 (each 64x64 = 2x2 frags of 32x32).
// LDS tile rows are 32 u16 (64 B) linear (gld_lds requirement); bank
// conflicts fixed by swizzling the per-lane GLOBAL source slot
// (sslot ^= srow&3) and reading slot (hi+2kc) ^ (row&3)  [rule #21:
// same involution on both sides; LDS dest stays linear].
// Loads for tile kt+2 issued at iter kt; barrier waits vmcnt(4).
// mbase/nbase computed by caller (2D XCD chunking).  LDS 49152 B.
// C layout (verified r10+): col = l31, row = (r&3)+8*(r>>2)+4*hi.
// ---------------------------------------------------------------------------
#define G3_ISSUE(KB, BUF)                                                            \
    gld_lds16(gA0 + (KB), sAb + (BUF) * 4096 + w * 512);                             \
    gld_lds16(gA1 + (KB), sAb + (BUF) * 4096 + (w + 4) * 512);                       \
    gld_lds16(gB0 + (KB), sBb + (BUF) * 4096 + w * 512);                             \
    gld_lds16(gB1 + (KB), sBb + (BUF) * 4096 + (w + 4) * 512);

#define G3_COMP(BUF)                                                                 \
    {                                                                                \
        const int rsw = l31 & 3;                                                     \
        const u16* pa = sAb + (BUF) * 4096 + (wm * 64 + l31) * 32;                   \
        const u16* pb = sBb + (BUF) * 4096 + (wn * 64 + l31) * 32;                   \
        s16x8 afr[2][2], bfr[2][2];                                                  \
        _Pragma("unroll")                                                            \
        for (int mi = 0; mi < 2; ++mi)                                               \
            _Pragma("unroll")                                                        \
            for (int kc = 0; kc < 2; ++kc) {                                         \
                const int sl = ((hi + 2 * kc) ^ rsw) * 8;                            \
                afr[mi][kc] = *(const s16x8*)(pa + mi * 1024 + sl);                  \
                bfr[mi][kc] = *(const s16x8*)(pb + mi * 1024 + sl);                  \
            }                                                                        \
        _Pragma("unroll")                                                            \
        for (int mi = 0; mi < 2; ++mi)                                               \
            _Pragma("unroll")                                                        \
            for (int nj = 0; nj < 2; ++nj)                                           \
                _Pragma("unroll")                                                    \
                for (int kc = 0; kc < 2; ++kc)                                       \
                    acc[mi][nj] = __builtin_amdgcn_mfma_f32_32x32x16_bf16(           \
                        afr[mi][kc], bfr[nj][kc], acc[mi][nj], 0, 0, 0);             \
    }

#define G3_BAR4                                                                      \
    asm volatile("s_waitcnt vmcnt(4) lgkmcnt(0)" ::: "memory");                      \
    __builtin_amdgcn_s_barrier();                                                    \
    __builtin_amdgcn_sched_barrier(0);

#define G3_BAR0                                                                      \
    asm volatile("s_waitcnt vmcnt(0) lgkmcnt(0)" ::: "memory");                      \
    __builtin_amdgcn_s_barrier();                                                    \
    __builtin_amdgcn_sched_barrier(0);

// expects: int mbase, nbase already computed
#define GEMM_CORE3(A_, Bt_)                                                          \
    extern __shared__ char smem[];                                                   \
    u16* sAb = (u16*)smem;                   /* 3 x [128*32] u16 */                  \
    u16* sBb = (u16*)(smem + 24576);         /* 3 x [128*32] u16 */                  \
    const int t = threadIdx.x;                                                       \
    const int lane = t & 63;                                                         \
    const int w = t >> 6;                                                            \
    const int wm = w >> 1, wn = w & 1;                                               \
    const int l31 = lane & 31, hi = lane >> 5;                                       \
    const int srow = lane >> 2;                                                      \
    const int sslot = (lane & 3) ^ (srow & 3);    /* source-side swizzle */          \
    const u16* gA0 = (A_) + (size_t)(mbase + w * 16 + srow) * 768 + sslot * 8;       \
    const u16* gA1 = gA0 + (size_t)64 * 768;                                         \
    const u16* gB0 = (Bt_) + (size_t)(nbase + w * 16 + srow) * 768 + sslot * 8;      \
    const u16* gB1 = gB0 + (size_t)64 * 768;                                         \
    f32x16 acc[2][2] = {};                                                           \
    G3_ISSUE(0, 0)                                                                   \
    G3_ISSUE(32, 1)                                                                  \
    G3_BAR4                                                                          \
    for (int k3 = 0; k3 < 7; ++k3) {                                                 \
        const int kb = k3 * 96;                                                      \
        G3_ISSUE(kb + 64, 2)  G3_COMP(0)  G3_BAR4                                    \
        G3_ISSUE(kb + 96, 0)  G3_COMP(1)  G3_BAR4                                    \
        G3_ISSUE(kb + 128, 1) G3_COMP(2)  G3_BAR4                                    \
    }                                                                                \
    G3_ISSUE(736, 2) G3_COMP(0) G3_BAR4                                              \
    G3_COMP(1) G3_BAR0                                                               \
    G3_COMP(2) G3_BAR0

// qkv = x @ w_qkv + b_qkv; bf16 q/k [b][p][64], v transposed [b][64][p];
// coalesced epilogue through LDS tile T[128][136].
// 2D XCD chunk: 8 XCDs as 4(m) x 2(n); region 16 m-tiles x 9 n-tiles.
__global__ __launch_bounds__(256) void gemm_qkv(const u16* __restrict__ A,
                                                const u16* __restrict__ Bt,
                                                const float* __restrict__ bias,
                                                u16* __restrict__ qout,
                                                u16* __restrict__ kout,
                                                u16* __restrict__ vout) {
    const int xcd = blockIdx.x & 7;
    const int local = blockIdx.x >> 3;                 // 0..143
    const int mbase = (((xcd >> 1) << 4) + (local & 15)) * 128;
    const int nbase = ((xcd & 1) * 9 + (local >> 4)) * 128;
    GEMM_CORE3(A, Bt)
    u16* T = (u16*)smem;

    const int which = nbase / C_;
    const int head0 = (nbase % C_) >> 6;
    const int n_img = mbase >> 10;
    const int pbase = mbase & 1023;

    if (which < 2) {
        #pragma unroll
        for (int mi = 0; mi < 2; ++mi)
            #pragma unroll
            for (int nj = 0; nj < 2; ++nj)
                #pragma unroll
                for (int r = 0; r < 16; ++r) {
                    const int lm = wm * 64 + mi * 32 + ((r & 3) + 8 * (r >> 2) + 4 * hi);
                    const int lc = wn * 64 + nj * 32 + l31;
                    T[lm * 136 + lc] = f2b(acc[mi][nj][r] + bias[nbase + lc]);
                }
    } else {
        #pragma unroll
        for (int mi = 0; mi < 2; ++mi)
            #pragma unroll
            for (int nj = 0; nj < 2; ++nj)
                #pragma unroll
                for (int r = 0; r < 16; ++r) {
                    const int lm = wm * 64 + mi * 32 + ((r & 3) + 8 * (r >> 2) + 4 * hi);
                    const int lc = wn * 64 + nj * 32 + l31;
                    T[lc * 136 + lm] = f2b(acc[mi][nj][r] + bias[nbase + lc]);
                }
    }
    __syncthreads();

    if (which < 2) {
        u16* dst = (which == 0) ? qout : kout;
        #pragma unroll
        for (int pass = 0; pass < 4; ++pass) {
            const int lm = pass * 32 + (t >> 3);
            #pragma unroll
            for (int hh = 0; hh < 2; ++hh) {
                s16x8 row = *(const s16x8*)(T + lm * 136 + hh * 64 + (t & 7) * 8);
                const size_t bidx = (size_t)(n_img * NH_ + head0 + hh);
                *(s16x8*)(dst + (bidx * HW_ + pbase + lm) * HD_ + (t & 7) * 8) = row;
            }
        }
    } else {
        #pragma unroll
        for (int pass = 0; pass < 8; ++pass) {
            const int lc = pass * 16 + (t >> 4);
            s16x8 row = *(const s16x8*)(T + lc * 136 + (t & 15) * 8);
            const int hh = lc >> 6, d = lc & 63;
            const size_t bidx = (size_t)(n_img * NH_ + head0 + hh);
            *(s16x8*)(vout + bidx * (size_t)(HW_ * HD_) + (size_t)d * HW_ + pbase + (t & 15) * 8) = row;
        }
    }
}

// out = o @ w_proj + b_proj, fp32 out.  2D XCD chunk: 8(m) x 6(n) per XCD.
__global__ __launch_bounds__(256) void gemm_proj(const u16* __restrict__ A,
                                                 const u16* __restrict__ Bt,
                                                 const float* __restrict__ bias,
                                                 float* __restrict__ out) {
    const int xcd = blockIdx.x & 7;
    const int local = blockIdx.x >> 3;                 // 0..47
    const int mbase = (xcd * 8 + (local & 7)) * 128;
    const int nbase = (local >> 3) * 128;
    GEMM_CORE3(A, Bt)
    #pragma unroll
    for (int mi = 0; mi < 2; ++mi)
        #pragma unroll
        for (int nj = 0; nj < 2; ++nj)
            #pragma unroll
            for (int r = 0; r < 16; ++r) {
                const int m = mbase + wm * 64 + mi * 32 + ((r & 3) + 8 * (r >> 2) + 4 * hi);
                const int n = nbase + wn * 64 + nj * 32 + l31;
                out[(size_t)m * C_ + n] = acc[mi][nj][r] + bias[n];
            }
}

// ---------------------------------------------------------------------------
// ef_gemm: F = Q @ rel_h^T, E = Q @ rel_w^T (x LOG2E), bf16 out [98304][64].
// ---------------------------------------------------------------------------
__global__ __launch_bounds__(256) void ef_gemm(const u16* __restrict__ qb_,
                                               const float* __restrict__ rel_h,
                                               const float* __restrict__ rel_w,
                                               u16* __restrict__ Fg,
                                               u16* __restrict__ Eg) {
    const int t = threadIdx.x;
    const int lane = t & 63;
    const int w = t >> 6;
    const int l31 = lane & 31;
    const int hi  = lane >> 5;
    const size_t Mrow = (size_t)blockIdx.x * 128 + w * 32 + l31;

    s16x8 qb[4];
    {
        const u16* qrow = qb_ + Mrow * HD_;
        #pragma unroll
        for (int ck = 0; ck < 4; ++ck)
            qb[ck] = *(const s16x8*)(qrow + ck * 16 + hi * 8);
    }

    #pragma unroll
    for (int tb = 0; tb < 2; ++tb) {
        const float* R = tb ? rel_w : rel_h;
        u16* og = (tb ? Eg : Fg) + Mrow * 64;
        #pragma unroll
        for (int hh = 0; hh < 2; ++hh) {
            const int dr = hh * 32 + l31;
            const float* rrow = R + (size_t)(dr > 62 ? 62 : dr) * HD_;
            f32x16 acc = {};
            #pragma unroll
            for (int ck = 0; ck < 4; ++ck) {
                float4 r0 = *(const float4*)(rrow + ck * 16 + hi * 8);
                float4 r1 = *(const float4*)(rrow + ck * 16 + hi * 8 + 4);
                s16x8 af;
                af[0] = (short)f2b(r0.x * LOG2E_); af[1] = (short)f2b(r0.y * LOG2E_);
                af[2] = (short)f2b(r0.z * LOG2E_); af[3] = (short)f2b(r0.w * LOG2E_);
                af[4] = (short)f2b(r1.x * LOG2E_); af[5] = (short)f2b(r1.y * LOG2E_);
                af[6] = (short)f2b(r1.z * LOG2E_); af[7] = (short)f2b(r1.w * LOG2E_);
                acc = __builtin_amdgcn_mfma_f32_32x32x16_bf16(af, qb[ck], acc, 0, 0, 0);
            }
            #pragma unroll
            for (int u = 0; u < 4; ++u) {
                u32x2 pkd;
                pkd.x = cvtpk(acc[4*u+0], acc[4*u+1]);
                pkd.y = cvtpk(acc[4*u+2], acc[4*u+3]);
                *(u32x2*)(og + hh * 32 + u * 8 + 4 * hi) = pkd;
            }
        }
    }
}

// ---------------------------------------------------------------------------
// attn — unchanged from round 17 (dbuf + raw barrier + E/F tables + setprio
// + cvt_pk P pack + MFMA row-sum).
// ---------------------------------------------------------------------------
__global__ __launch_bounds__(256) void attn_mfma(const u16* __restrict__ qb_,
                                                 const u16* __restrict__ kbf,
                                                 const u16* __restrict__ vtb,
                                                 const u16* __restrict__ Fg,
                                                 const u16* __restrict__ Eg,
                                                 u16* __restrict__ ob) {
    extern __shared__ char smem[];
    u16*   sBH  = (u16*)smem;
    u16*   sK0  = (u16*)(smem + 8704);
    u16*   sK1  = (u16*)(smem + 17920);
    u16*   sVt0 = (u16*)(smem + 27136);
    u16*   sVt1 = (u16*)(smem + 36352);

    const int t = threadIdx.x;
    const int lane = t & 63;
    const int w = t >> 6;
    const int l31 = lane & 31;
    const int hi  = lane >> 5;
    const int qw  = w * 32;

    const int bid = blockIdx.x;
    const int swz = (bid & 7) * 96 + (bid >> 3);
    const int b = swz >> 3;
    const int qbase = (swz & 7) * 128;

    s16x8 qfr[4];
    {
        const u16* qrow = qb_ + ((size_t)b * HW_ + qbase + qw + l31) * HD_;
        #pragma unroll
        for (int ck = 0; ck < 4; ++ck) {
            s16x8 qv = *(const s16x8*)(qrow + ck * 16 + hi * 8);
            #pragma unroll
            for (int e = 0; e < 8; ++e)
                qfr[ck][e] = (short)f2b(b2f((u16)qv[e]) * (SCALE_ * LOG2E_));
        }
    }

    {
        const u16* Fb = Fg + (size_t)b * HW_ * 64;
        for (int idv = t; idv < 4096; idv += 256) {
            const int row = idv >> 5;
            const int kh  = idv & 31;
            const int qg  = qbase + row;
            sBH[row * 34 + kh] = Fb[(size_t)qg * 64 + (qg >> 5) + 31 - kh];
        }
    }

    f32x4 bwv[4];
    {
        const int qmy = qbase + qw + l31;
        const u16* Erow = Eg + (size_t)(b * HW_ + qmy) * 64;
        #pragma unroll
        for (int m = 0; m < 4; ++m)
            #pragma unroll
            for (int j = 0; j < 4; ++j)
                bwv[m][j] = b2f(Erow[l31 + 31 - (m * 8 + 4 * hi + j)]);
    }

    const int srow = t >> 2;
    const int sc0  = (t & 3) * 16;
    const u16* kg = kbf + ((size_t)b * HW_ + srow) * HD_ + sc0;
    const u16* vg = vtb + (size_t)b * HD_ * HW_ + (size_t)srow * HW_ + sc0;
    u16* skw0 = sK0  + srow * 72 + sc0;
    u16* skw1 = sK1  + srow * 72 + sc0;
    u16* svw0 = sVt0 + srow * 72 + sc0;
    u16* svw1 = sVt1 + srow * 72 + sc0;

    s16x8 kr0 = *(const s16x8*)(kg);
    s16x8 kr1 = *(const s16x8*)(kg + 8);
    s16x8 vr0 = *(const s16x8*)(vg);
    s16x8 vr1 = *(const s16x8*)(vg + 8);
    *(s16x8*)(skw0)     = kr0;
    *(s16x8*)(skw0 + 8) = kr1;
    *(s16x8*)(svw0)     = vr0;
    *(s16x8*)(svw0 + 8) = vr1;
    __syncthreads();

    f32x16 Oacc[2] = {};
    f32x16 Osum = {};
    const u32x4 onesu = {0x3F803F80u, 0x3F803F80u, 0x3F803F80u, 0x3F803F80u};
    const s16x8 ones = *reinterpret_cast<const s16x8*>(&onesu);
    const int bhbase = (qw + l31) * 34;

    auto body = [&](int kt, const u16* sKr, const u16* sVr, u16* skwN, u16* svwN) {
        if (kt < 15) {
            const u16* kn = kg + (size_t)(kt + 1) * 64 * HD_;
            kr0 = *(const s16x8*)(kn);
            kr1 = *(const s16x8*)(kn + 8);
            const u16* vn = vg + (size_t)(kt + 1) * 64;
            vr0 = *(const s16x8*)(vn);
            vr1 = *(const s16x8*)(vn + 8);
        }

        const float bh0 = b2f(sBH[bhbase + 2 * kt]);
        const float bh1 = b2f(sBH[bhbase + 2 * kt + 1]);

        #pragma unroll
        for (int kvt = 0; kvt < 2; ++kvt) {
            f32x16 s = {};
            __builtin_amdgcn_s_setprio(1);
            #pragma unroll
            for (int ck = 0; ck < 4; ++ck) {
                s16x8 kf = *(const s16x8*)(sKr + (kvt * 32 + l31) * 72 + ck * 16 + hi * 8);
                s = __builtin_amdgcn_mfma_f32_32x32x16_bf16(kf, qfr[ck], s, 0, 0, 0);
            }
            __builtin_amdgcn_s_setprio(0);
            const float bh = kvt ? bh1 : bh0;

            u32 pw[8];
            #pragma unroll
            for (int m = 0; m < 8; ++m) {
                float p0 = __builtin_amdgcn_exp2f(s[2*m]   + bh + bwv[(2*m)>>2][(2*m)&3]);
                float p1 = __builtin_amdgcn_exp2f(s[2*m+1] + bh + bwv[(2*m+1)>>2][(2*m+1)&3]);
                pw[m] = cvtpk(p0, p1);
            }

            __builtin_amdgcn_s_setprio(1);
            #pragma unroll
            for (int cc = 0; cc < 2; ++cc) {
                i32x2 s02 = __builtin_amdgcn_permlane32_swap((int)pw[cc*4+0], (int)pw[cc*4+2], false, false);
                i32x2 s13 = __builtin_amdgcn_permlane32_swap((int)pw[cc*4+1], (int)pw[cc*4+3], false, false);
                u32x4 pau;
                pau.x = (u32)s02.x; pau.y = (u32)s13.x;
                pau.z = (u32)s02.y; pau.w = (u32)s13.y;
                s16x8 pa = *reinterpret_cast<s16x8*>(&pau);
                const int kc = kvt * 2 + cc;
                #pragma unroll
                for (int dt = 0; dt < 2; ++dt) {
                    s16x8 vf = *(const s16x8*)(sVr + (dt * 32 + l31) * 72 + kc * 16 + hi * 8);
                    Oacc[dt] = __builtin_amdgcn_mfma_f32_32x32x16_bf16(pa, vf, Oacc[dt], 0, 0, 0);
                }
                Osum = __builtin_amdgcn_mfma_f32_32x32x16_bf16(pa, ones, Osum, 0, 0, 0);
            }
            __builtin_amdgcn_s_setprio(0);
        }

        if (kt < 15) {
            *(s16x8*)(skwN)     = kr0;
            *(s16x8*)(skwN + 8) = kr1;
            *(s16x8*)(svwN)     = vr0;
            *(s16x8*)(svwN + 8) = vr1;
        }
        asm volatile("s_waitcnt lgkmcnt(0)" ::: "memory");
        __builtin_amdgcn_s_barrier();
        __builtin_amdgcn_sched_barrier(0);
    };

    for (int k2 = 0; k2 < 8; ++k2) {
        body(2 * k2,     sK0, sVt0, skw1, svw1);
        body(2 * k2 + 1, sK1, sVt1, skw0, svw0);
    }

    const int n_img = b / NH_;
    const int head  = b % NH_;
    #pragma unroll
    for (int dt = 0; dt < 2; ++dt) {
        #pragma unroll
        for (int r = 0; r < 16; ++r) {
            const int qloc = (r & 3) + 8 * (r >> 2) + 4 * hi;
            const int qg = qbase + qw + qloc;
            ob[(size_t)(n_img * HW_ + qg) * C_ + head * HD_ + dt * 32 + l31] =
                f2b(Oacc[dt][r] / Osum[r]);
        }
    }
}

extern "C" void kernel_launch(void* const* d_in, const int* in_sizes, int n_in,
                              void* d_out, int out_size, void* d_ws, size_t ws_size,
                              hipStream_t stream) {
    const float* x      = (const float*)d_in[0];
    const float* w_qkv  = (const float*)d_in[1];
    const float* b_qkv  = (const float*)d_in[2];
    const float* w_proj = (const float*)d_in[3];
    const float* b_proj = (const float*)d_in[4];
    const float* rel_h  = (const float*)d_in[5];
    const float* rel_w  = (const float*)d_in[6];
    float* out = (float*)d_out;

    const size_t seg = (size_t)B_ * HW_ * HD_;   // 6,291,456
    char* p = (char*)d_ws;
    u16* xb     = (u16*)p;  p += seg * 2;
    u16* wqkvT  = (u16*)p;  p += (size_t)C3_ * C_ * 2;
    u16* wprojT = (u16*)p;  p += (size_t)C_ * C_ * 2;
    u16* qb     = (u16*)p;  p += seg * 2;
    u16* kbf    = (u16*)p;  p += seg * 2;
    u16* vtb    = (u16*)p;  p += seg * 2;
    u16* ob     = (u16*)p;  p += seg * 2;
    u16* Fg     = (u16*)p;  p += seg * 2;
    u16* Eg     = (u16*)p;  p += seg * 2;

    cvt_bf16<<<2048, 256, 0, stream>>>(x, xb, (int)(seg / 4));
    tcvt_bf16<<<dim3(C3_ / 64, C_ / 64), 256, 0, stream>>>(w_qkv, wqkvT, C_, C3_);
    tcvt_bf16<<<dim3(C_ / 64, C_ / 64), 256, 0, stream>>>(w_proj, wprojT, C_, C_);

    gemm_qkv<<<1152, 256, 49152, stream>>>(xb, wqkvT, b_qkv, qb, kbf, vtb);
    ef_gemm<<<768, 256, 0, stream>>>(qb, rel_h, rel_w, Fg, Eg);
    attn_mfma<<<768, 256, 45568, stream>>>(qb, kbf, vtb, Fg, Eg, ob);
    gemm_proj<<<384, 256, 49152, stream>>>(ob, wprojT, b_proj, out);
}

// Round 20
// 138.302 us; speedup vs baseline: 1.0531x; 1.0531x over previous
//
#include <hip/hip_runtime.h>
#include <hip/hip_bf16.h>

#define N_    8
#define H_    32
#define W_    32
#define C_    768
#define NH_   12
#define HD_   64
#define B_    96      // N_*NH_
#define HW_   1024
#define C3_   2304
#define SCALE_ 0.125f
#define LOG2E_ 1.4426950408889634f

typedef __attribute__((ext_vector_type(4))) float f32x4;
typedef __attribute__((ext_vector_type(16))) float f32x16;
typedef __attribute__((ext_vector_type(8))) short s16x8;
typedef __attribute__((ext_vector_type(2))) int i32x2;
typedef __attribute__((ext_vector_type(2))) unsigned int u32x2;
typedef __attribute__((ext_vector_type(4))) unsigned int u32x4;
typedef unsigned short u16;
typedef unsigned int u32;

__device__ inline u16 f2b(float x) {
    __hip_bfloat16 h = __float2bfloat16(x);
    return *reinterpret_cast<u16*>(&h);
}
__device__ inline float b2f(u16 x) {
    u32 u = ((u32)x) << 16;
    return *reinterpret_cast<float*>(&u);
}
__device__ __forceinline__ u32 cvtpk(float a, float b) {
    u32 r;
    asm("v_cvt_pk_bf16_f32 %0, %1, %2" : "=v"(r) : "v"(a), "v"(b));
    return r;
}

__device__ __forceinline__ void gld_lds16(const void* g, void* l) {
    __builtin_amdgcn_global_load_lds(
        (const __attribute__((address_space(1))) u32*)g,
        (__attribute__((address_space(3))) u32*)l, 16, 0, 0);
}

// ---------------------------------------------------------------------------
// prep_fused: one kernel for (a) x fp32->bf16, (b) w_qkv transpose-convert,
// (c) w_proj transpose-convert.  Partitioned by blockIdx range.
// ---------------------------------------------------------------------------
__global__ __launch_bounds__(256) void prep_fused(const float* __restrict__ x,
                                                  u16* __restrict__ xb,
                                                  const float* __restrict__ w_qkv,
                                                  u16* __restrict__ wqkvT,
                                                  const float* __restrict__ w_proj,
                                                  u16* __restrict__ wprojT) {
    __shared__ u16 tile[64][72];
    const int t = threadIdx.x;
    const int bid = blockIdx.x;
    if (bid < 2048) {
        const int n4 = (int)((size_t)B_ * HW_ * HD_ / 4);
        for (int i = bid * 256 + t; i < n4; i += 2048 * 256) {
            float4 v = ((const float4*)x)[i];
            ushort4 o;
            o.x = f2b(v.x); o.y = f2b(v.y); o.z = f2b(v.z); o.w = f2b(v.w);
            ((ushort4*)xb)[i] = o;
        }
        return;
    }
    int rem = bid - 2048;
    const float* in;
    u16* outp;
    int N, n0, k0;
    if (rem < 432) { in = w_qkv;  outp = wqkvT;  N = C3_; n0 = (rem % 36) * 64; k0 = (rem / 36) * 64; }
    else { rem -= 432; in = w_proj; outp = wprojT; N = C_;  n0 = (rem % 12) * 64; k0 = (rem / 12) * 64; }
    const int r = t >> 2, c4 = (t & 3) * 16;
    #pragma unroll
    for (int u = 0; u < 4; ++u) {
        float4 v = *(const float4*)(in + (size_t)(k0 + r) * N + n0 + c4 + u * 4);
        tile[c4 + u*4 + 0][r] = f2b(v.x);
        tile[c4 + u*4 + 1][r] = f2b(v.y);
        tile[c4 + u*4 + 2][r] = f2b(v.z);
        tile[c4 + u*4 + 3][r] = f2b(v.w);
    }
    __syncthreads();
    #pragma unroll
    for (int u = 0; u < 2; ++u) {
        s16x8 v;
        #pragma unroll
        for (int e = 0; e < 8; ++e) v[e] = (short)tile[r][c4 + u*8 + e];
        *(s16x8*)(outp + (size_t)(n0 + r) * 768 + k0 + c4 + u*8) = v;
    }
}

// ---------------------------------------------------------------------------
// GEMM core, 3-DEEP pipeline (r17-verified, 16x16x32 MFMA): 128x128 tile,
// BK=32, 4 waves 2x2.  Loads for tile kt+2 issued at iter kt; barrier waits
// vmcnt(4).  Raw s_barrier + lgkmcnt(0) + sched_barrier(0).  1D XCD swizzle.
// Dynamic LDS: 3x(8KB A + 8KB B) = 49152 B.  K = 768 (24 steps).
// ---------------------------------------------------------------------------
#define G3_ISSUE(KB, BUF)                                                            \
    gld_lds16(gA0 + (KB), sAb + (BUF) * 4096 + w * 512);                             \
    gld_lds16(gA1 + (KB), sAb + (BUF) * 4096 + (w + 4) * 512);                       \
    gld_lds16(gB0 + (KB), sBb + (BUF) * 4096 + w * 512);                             \
    gld_lds16(gB1 + (KB), sBb + (BUF) * 4096 + (w + 4) * 512);

#define G3_COMP(BUF)                                                                 \
    {                                                                                \
        const u16* pa = sAb + (BUF) * 4096 + (wm * 64 + l15) * 32 + lg * 8;          \
        const u16* pb = sBb + (BUF) * 4096 + (wn * 64 + l15) * 32 + lg * 8;          \
        s16x8 afr[4], bfr[4];                                                        \
        _Pragma("unroll")                                                            \
        for (int i = 0; i < 4; ++i) {                                                \
            afr[i] = *(const s16x8*)(pa + i * 512);                                  \
            bfr[i] = *(const s16x8*)(pb + i * 512);                                  \
        }                                                                            \
        _Pragma("unroll")                                                            \
        for (int i = 0; i < 4; ++i)                                                  \
            _Pragma("unroll")                                                        \
            for (int j = 0; j < 4; ++j)                                              \
                acc[i][j] = __builtin_amdgcn_mfma_f32_16x16x32_bf16(afr[i], bfr[j],  \
                                                                    acc[i][j], 0, 0, 0); \
    }

#define G3_BAR4                                                                      \
    asm volatile("s_waitcnt vmcnt(4) lgkmcnt(0)" ::: "memory");                      \
    __builtin_amdgcn_s_barrier();                                                    \
    __builtin_amdgcn_sched_barrier(0);

#define G3_BAR0                                                                      \
    asm volatile("s_waitcnt vmcnt(0) lgkmcnt(0)" ::: "memory");                      \
    __builtin_amdgcn_s_barrier();                                                    \
    __builtin_amdgcn_sched_barrier(0);

#define GEMM_CORE3(A_, Bt_, NT_)                                                     \
    extern __shared__ char smem[];                                                   \
    u16* sAb = (u16*)smem;                   /* 3 x [128*32] u16 */                  \
    u16* sBb = (u16*)(smem + 24576);         /* 3 x [128*32] u16 */                  \
    const int t = threadIdx.x;                                                       \
    const int lane = t & 63;                                                         \
    const int w = t >> 6;                                                            \
    const int wm = w >> 1, wn = w & 1;                                               \
    const int l15 = lane & 15, lg = lane >> 4;                                       \
    const int per = (int)gridDim.x >> 3;                                             \
    const int swz = ((int)blockIdx.x & 7) * per + ((int)blockIdx.x >> 3);            \
    const int nbase = (swz % (NT_)) * 128;                                           \
    const int mbase = (swz / (NT_)) * 128;                                           \
    const int srow = lane >> 2;                                                      \
    const int sslot = lane & 3;                                                      \
    const u16* gA0 = (A_) + (size_t)(mbase + w * 16 + srow) * 768 + sslot * 8;       \
    const u16* gA1 = gA0 + (size_t)64 * 768;                                         \
    const u16* gB0 = (Bt_) + (size_t)(nbase + w * 16 + srow) * 768 + sslot * 8;      \
    const u16* gB1 = gB0 + (size_t)64 * 768;                                         \
    f32x4 acc[4][4] = {};                                                            \
    G3_ISSUE(0, 0)                                                                   \
    G3_ISSUE(32, 1)                                                                  \
    G3_BAR4                                                                          \
    for (int k3 = 0; k3 < 7; ++k3) {                                                 \
        const int kb = k3 * 96;                                                      \
        G3_ISSUE(kb + 64, 2)  G3_COMP(0)  G3_BAR4                                    \
        G3_ISSUE(kb + 96, 0)  G3_COMP(1)  G3_BAR4                                    \
        G3_ISSUE(kb + 128, 1) G3_COMP(2)  G3_BAR4                                    \
    }                                                                                \
    G3_ISSUE(736, 2) G3_COMP(0) G3_BAR4                                              \
    G3_COMP(1) G3_BAR0                                                               \
    G3_COMP(2) G3_BAR0

// qkv = x @ w_qkv + b_qkv; bf16 q/k [b][p][64], v transposed [b][64][p];
// coalesced epilogue through LDS tile T[128][136].  which==0 blocks ALSO
// compute the fused E/F bias tables for their 128 rows x 2 heads (q is
// already bf16 in T — same math as the old ef_gemm, q sourced from LDS).
__global__ __launch_bounds__(256) void gemm_qkv(const u16* __restrict__ A,
                                                const u16* __restrict__ Bt,
                                                const float* __restrict__ bias,
                                                const float* __restrict__ rel_h,
                                                const float* __restrict__ rel_w,
                                                u16* __restrict__ qout,
                                                u16* __restrict__ kout,
                                                u16* __restrict__ vout,
                                                u16* __restrict__ Fg,
                                                u16* __restrict__ Eg) {
    GEMM_CORE3(A, Bt, 18)
    u16* T = (u16*)smem;

    const int which = nbase / C_;
    const int head0 = (nbase % C_) >> 6;
    const int n_img = mbase >> 10;
    const int pbase = mbase & 1023;

    if (which < 2) {
        #pragma unroll
        for (int i = 0; i < 4; ++i)
            #pragma unroll
            for (int r = 0; r < 4; ++r) {
                const int lm = wm * 64 + i * 16 + lg * 4 + r;
                #pragma unroll
                for (int j = 0; j < 4; ++j) {
                    const int lc = wn * 64 + j * 16 + l15;
                    T[lm * 136 + lc] = f2b(acc[i][j][r] + bias[nbase + lc]);
                }
            }
    } else {
        #pragma unroll
        for (int i = 0; i < 4; ++i)
            #pragma unroll
            for (int r = 0; r < 4; ++r) {
                const int lm = wm * 64 + i * 16 + lg * 4 + r;
                #pragma unroll
                for (int j = 0; j < 4; ++j) {
                    const int lc = wn * 64 + j * 16 + l15;
                    T[lc * 136 + lm] = f2b(acc[i][j][r] + bias[nbase + lc]);
                }
            }
    }
    __syncthreads();

    if (which < 2) {
        u16* dst = (which == 0) ? qout : kout;
        #pragma unroll
        for (int pass = 0; pass < 4; ++pass) {
            const int lm = pass * 32 + (t >> 3);
            #pragma unroll
            for (int hh = 0; hh < 2; ++hh) {
                s16x8 row = *(const s16x8*)(T + lm * 136 + hh * 64 + (t & 7) * 8);
                const size_t bidx = (size_t)(n_img * NH_ + head0 + hh);
                *(s16x8*)(dst + (bidx * HW_ + pbase + lm) * HD_ + (t & 7) * 8) = row;
            }
        }
    } else {
        #pragma unroll
        for (int pass = 0; pass < 8; ++pass) {
            const int lc = pass * 16 + (t >> 4);
            s16x8 row = *(const s16x8*)(T + lc * 136 + (t & 15) * 8);
            const int hh = lc >> 6, d = lc & 63;
            const size_t bidx = (size_t)(n_img * NH_ + head0 + hh);
            *(s16x8*)(vout + bidx * (size_t)(HW_ * HD_) + (size_t)d * HW_ + pbase + (t & 15) * 8) = row;
        }
    }

    // ---- fused EF (q blocks only): F/E for these 128 rows x 2 heads.
    // Math identical to the old ef_gemm (verified r14-r19); q read from T.
    if (which == 0) {
        const int l31e = lane & 31;
        const int hie  = lane >> 5;
        #pragma unroll
        for (int hh2 = 0; hh2 < 2; ++hh2) {
            s16x8 qfe[4];
            #pragma unroll
            for (int ck = 0; ck < 4; ++ck)
                qfe[ck] = *(const s16x8*)(T + (w * 32 + l31e) * 136 + hh2 * 64 + ck * 16 + hie * 8);
            const size_t rowbase =
                ((size_t)(n_img * NH_ + head0 + hh2) * HW_ + pbase + w * 32 + l31e) * 64;
            #pragma unroll
            for (int tb = 0; tb < 2; ++tb) {
                const float* R = tb ? rel_w : rel_h;
                u16* og = (tb ? Eg : Fg) + rowbase;
                #pragma unroll
                for (int hh = 0; hh < 2; ++hh) {
                    const int dr = hh * 32 + l31e;
                    const float* rrow = R + (size_t)(dr > 62 ? 62 : dr) * HD_;
                    f32x16 acce = {};
                    #pragma unroll
                    for (int ck = 0; ck < 4; ++ck) {
                        float4 r0 = *(const float4*)(rrow + ck * 16 + hie * 8);
                        float4 r1 = *(const float4*)(rrow + ck * 16 + hie * 8 + 4);
                        s16x8 af;
                        af[0] = (short)f2b(r0.x * LOG2E_); af[1] = (short)f2b(r0.y * LOG2E_);
                        af[2] = (short)f2b(r0.z * LOG2E_); af[3] = (short)f2b(r0.w * LOG2E_);
                        af[4] = (short)f2b(r1.x * LOG2E_); af[5] = (short)f2b(r1.y * LOG2E_);
                        af[6] = (short)f2b(r1.z * LOG2E_); af[7] = (short)f2b(r1.w * LOG2E_);
                        acce = __builtin_amdgcn_mfma_f32_32x32x16_bf16(af, qfe[ck], acce, 0, 0, 0);
                    }
                    #pragma unroll
                    for (int u = 0; u < 4; ++u) {
                        u32x2 pkd;
                        pkd.x = cvtpk(acce[4*u+0], acce[4*u+1]);
                        pkd.y = cvtpk(acce[4*u+2], acce[4*u+3]);
                        *(u32x2*)(og + hh * 32 + u * 8 + 4 * hie) = pkd;
                    }
                }
            }
        }
    }
}

// out = o @ w_proj + b_proj, fp32 out (r17-verified)
__global__ __launch_bounds__(256) void gemm_proj(const u16* __restrict__ A,
                                                 const u16* __restrict__ Bt,
                                                 const float* __restrict__ bias,
                                                 float* __restrict__ out) {
    GEMM_CORE3(A, Bt, 6)
    const int mrow0 = mbase + wm * 64 + lg * 4;
    #pragma unroll
    for (int i = 0; i < 4; ++i) {
        #pragma unroll
        for (int r = 0; r < 4; ++r) {
            const int m = mrow0 + i * 16 + r;
            #pragma unroll
            for (int j = 0; j < 4; ++j) {
                const int n = nbase + wn * 64 + j * 16 + l15;
                out[(size_t)m * C_ + n] = acc[i][j][r] + bias[n];
            }
        }
    }
}

// ---------------------------------------------------------------------------
// attn — unchanged from round 17 (dbuf + raw barrier + E/F tables + setprio
// + cvt_pk P pack + MFMA row-sum).
// ---------------------------------------------------------------------------
__global__ __launch_bounds__(256) void attn_mfma(const u16* __restrict__ qb_,
                                                 const u16* __restrict__ kbf,
                                                 const u16* __restrict__ vtb,
                                                 const u16* __restrict__ Fg,
                                                 const u16* __restrict__ Eg,
                                                 u16* __restrict__ ob) {
    extern __shared__ char smem[];
    u16*   sBH  = (u16*)smem;
    u16*   sK0  = (u16*)(smem + 8704);
    u16*   sK1  = (u16*)(smem + 17920);
    u16*   sVt0 = (u16*)(smem + 27136);
    u16*   sVt1 = (u16*)(smem + 36352);

    const int t = threadIdx.x;
    const int lane = t & 63;
    const int w = t >> 6;
    const int l31 = lane & 31;
    const int hi  = lane >> 5;
    const int qw  = w * 32;

    const int bid = blockIdx.x;
    const int swz = (bid & 7) * 96 + (bid >> 3);
    const int b = swz >> 3;
    const int qbase = (swz & 7) * 128;

    s16x8 qfr[4];
    {
        const u16* qrow = qb_ + ((size_t)b * HW_ + qbase + qw + l31) * HD_;
        #pragma unroll
        for (int ck = 0; ck < 4; ++ck) {
            s16x8 qv = *(const s16x8*)(qrow + ck * 16 + hi * 8);
            #pragma unroll
            for (int e = 0; e < 8; ++e)
                qfr[ck][e] = (short)f2b(b2f((u16)qv[e]) * (SCALE_ * LOG2E_));
        }
    }

    {
        const u16* Fb = Fg + (size_t)b * HW_ * 64;
        for (int idv = t; idv < 4096; idv += 256) {
            const int row = idv >> 5;
            const int kh  = idv & 31;
            const int qg  = qbase + row;
            sBH[row * 34 + kh] = Fb[(size_t)qg * 64 + (qg >> 5) + 31 - kh];
        }
    }

    f32x4 bwv[4];
    {
        const int qmy = qbase + qw + l31;
        const u16* Erow = Eg + (size_t)(b * HW_ + qmy) * 64;
        #pragma unroll
        for (int m = 0; m < 4; ++m)
            #pragma unroll
            for (int j = 0; j < 4; ++j)
                bwv[m][j] = b2f(Erow[l31 + 31 - (m * 8 + 4 * hi + j)]);
    }

    const int srow = t >> 2;
    const int sc0  = (t & 3) * 16;
    const u16* kg = kbf + ((size_t)b * HW_ + srow) * HD_ + sc0;
    const u16* vg = vtb + (size_t)b * HD_ * HW_ + (size_t)srow * HW_ + sc0;
    u16* skw0 = sK0  + srow * 72 + sc0;
    u16* skw1 = sK1  + srow * 72 + sc0;
    u16* svw0 = sVt0 + srow * 72 + sc0;
    u16* svw1 = sVt1 + srow * 72 + sc0;

    s16x8 kr0 = *(const s16x8*)(kg);
    s16x8 kr1 = *(const s16x8*)(kg + 8);
    s16x8 vr0 = *(const s16x8*)(vg);
    s16x8 vr1 = *(const s16x8*)(vg + 8);
    *(s16x8*)(skw0)     = kr0;
    *(s16x8*)(skw0 + 8) = kr1;
    *(s16x8*)(svw0)     = vr0;
    *(s16x8*)(svw0 + 8) = vr1;
    __syncthreads();

    f32x16 Oacc[2] = {};
    f32x16 Osum = {};
    const u32x4 onesu = {0x3F803F80u, 0x3F803F80u, 0x3F803F80u, 0x3F803F80u};
    const s16x8 ones = *reinterpret_cast<const s16x8*>(&onesu);
    const int bhbase = (qw + l31) * 34;

    auto body = [&](int kt, const u16* sKr, const u16* sVr, u16* skwN, u16* svwN) {
        if (kt < 15) {
            const u16* kn = kg + (size_t)(kt + 1) * 64 * HD_;
            kr0 = *(const s16x8*)(kn);
            kr1 = *(const s16x8*)(kn + 8);
            const u16* vn = vg + (size_t)(kt + 1) * 64;
            vr0 = *(const s16x8*)(vn);
            vr1 = *(const s16x8*)(vn + 8);
        }

        const float bh0 = b2f(sBH[bhbase + 2 * kt]);
        const float bh1 = b2f(sBH[bhbase + 2 * kt + 1]);

        #pragma unroll
        for (int kvt = 0; kvt < 2; ++kvt) {
            f32x16 s = {};
            __builtin_amdgcn_s_setprio(1);
            #pragma unroll
            for (int ck = 0; ck < 4; ++ck) {
                s16x8 kf = *(const s16x8*)(sKr + (kvt * 32 + l31) * 72 + ck * 16 + hi * 8);
                s = __builtin_amdgcn_mfma_f32_32x32x16_bf16(kf, qfr[ck], s, 0, 0, 0);
            }
            __builtin_amdgcn_s_setprio(0);
            const float bh = kvt ? bh1 : bh0;

            u32 pw[8];
            #pragma unroll
            for (int m = 0; m < 8; ++m) {
                float p0 = __builtin_amdgcn_exp2f(s[2*m]   + bh + bwv[(2*m)>>2][(2*m)&3]);
                float p1 = __builtin_amdgcn_exp2f(s[2*m+1] + bh + bwv[(2*m+1)>>2][(2*m+1)&3]);
                pw[m] = cvtpk(p0, p1);
            }

            __builtin_amdgcn_s_setprio(1);
            #pragma unroll
            for (int cc = 0; cc < 2; ++cc) {
                i32x2 s02 = __builtin_amdgcn_permlane32_swap((int)pw[cc*4+0], (int)pw[cc*4+2], false, false);
                i32x2 s13 = __builtin_amdgcn_permlane32_swap((int)pw[cc*4+1], (int)pw[cc*4+3], false, false);
                u32x4 pau;
                pau.x = (u32)s02.x; pau.y = (u32)s13.x;
                pau.z = (u32)s02.y; pau.w = (u32)s13.y;
                s16x8 pa = *reinterpret_cast<s16x8*>(&pau);
                const int kc = kvt * 2 + cc;
                #pragma unroll
                for (int dt = 0; dt < 2; ++dt) {
                    s16x8 vf = *(const s16x8*)(sVr + (dt * 32 + l31) * 72 + kc * 16 + hi * 8);
                    Oacc[dt] = __builtin_amdgcn_mfma_f32_32x32x16_bf16(pa, vf, Oacc[dt], 0, 0, 0);
                }
                Osum = __builtin_amdgcn_mfma_f32_32x32x16_bf16(pa, ones, Osum, 0, 0, 0);
            }
            __builtin_amdgcn_s_setprio(0);
        }

        if (kt < 15) {
            *(s16x8*)(skwN)     = kr0;
            *(s16x8*)(skwN + 8) = kr1;
            *(s16x8*)(svwN)     = vr0;
            *(s16x8*)(svwN + 8) = vr1;
        }
        asm volatile("s_waitcnt lgkmcnt(0)" ::: "memory");
        __builtin_amdgcn_s_barrier();
        __builtin_amdgcn_sched_barrier(0);
    };

    for (int k2 = 0; k2 < 8; ++k2) {
        body(2 * k2,     sK0, sVt0, skw1, svw1);
        body(2 * k2 + 1, sK1, sVt1, skw0, svw0);
    }

    const int n_img = b / NH_;
    const int head  = b % NH_;
    #pragma unroll
    for (int dt = 0; dt < 2; ++dt) {
        #pragma unroll
        for (int r = 0; r < 16; ++r) {
            const int qloc = (r & 3) + 8 * (r >> 2) + 4 * hi;
            const int qg = qbase + qw + qloc;
            ob[(size_t)(n_img * HW_ + qg) * C_ + head * HD_ + dt * 32 + l31] =
                f2b(Oacc[dt][r] / Osum[r]);
        }
    }
}

extern "C" void kernel_launch(void* const* d_in, const int* in_sizes, int n_in,
                              void* d_out, int out_size, void* d_ws, size_t ws_size,
                              hipStream_t stream) {
    const float* x      = (const float*)d_in[0];
    const float* w_qkv  = (const float*)d_in[1];
    const float* b_qkv  = (const float*)d_in[2];
    const float* w_proj = (const float*)d_in[3];
    const float* b_proj = (const float*)d_in[4];
    const float* rel_h  = (const float*)d_in[5];
    const float* rel_w  = (const float*)d_in[6];
    float* out = (float*)d_out;

    const size_t seg = (size_t)B_ * HW_ * HD_;   // 6,291,456
    char* p = (char*)d_ws;
    u16* xb     = (u16*)p;  p += seg * 2;
    u16* wqkvT  = (u16*)p;  p += (size_t)C3_ * C_ * 2;
    u16* wprojT = (u16*)p;  p += (size_t)C_ * C_ * 2;
    u16* qb     = (u16*)p;  p += seg * 2;
    u16* kbf    = (u16*)p;  p += seg * 2;
    u16* vtb    = (u16*)p;  p += seg * 2;
    u16* ob     = (u16*)p;  p += seg * 2;
    u16* Fg     = (u16*)p;  p += seg * 2;
    u16* Eg     = (u16*)p;  p += seg * 2;

    prep_fused<<<2624, 256, 0, stream>>>(x, xb, w_qkv, wqkvT, w_proj, wprojT);
    gemm_qkv<<<1152, 256, 49152, stream>>>(xb, wqkvT, b_qkv, rel_h, rel_w,
                                           qb, kbf, vtb, Fg, Eg);
    attn_mfma<<<768, 256, 45568, stream>>>(qb, kbf, vtb, Fg, Eg, ob);
    gemm_proj<<<384, 256, 49152, stream>>>(ob, wprojT, b_proj, out);
}

// Round 21
// 137.855 us; speedup vs baseline: 1.0565x; 1.0032x over previous
//
#include <hip/hip_runtime.h>
#include <hip/hip_bf16.h>

#define N_    8
#define H_    32
#define W_    32
#define C_    768
#define NH_   12
#define HD_   64
#define B_    96      // N_*NH_
#define HW_   1024
#define C3_   2304
#define SCALE_ 0.125f
#define LOG2E_ 1.4426950408889634f

typedef __attribute__((ext_vector_type(4))) float f32x4;
typedef __attribute__((ext_vector_type(16))) float f32x16;
typedef __attribute__((ext_vector_type(8))) short s16x8;
typedef __attribute__((ext_vector_type(2))) int i32x2;
typedef __attribute__((ext_vector_type(2))) unsigned int u32x2;
typedef __attribute__((ext_vector_type(4))) unsigned int u32x4;
typedef unsigned short u16;
typedef unsigned int u32;

__device__ inline u16 f2b(float x) {
    __hip_bfloat16 h = __float2bfloat16(x);
    return *reinterpret_cast<u16*>(&h);
}
__device__ inline float b2f(u16 x) {
    u32 u = ((u32)x) << 16;
    return *reinterpret_cast<float*>(&u);
}
__device__ __forceinline__ u32 cvtpk(float a, float b) {
    u32 r;
    asm("v_cvt_pk_bf16_f32 %0, %1, %2" : "=v"(r) : "v"(a), "v"(b));
    return r;
}

__device__ __forceinline__ void gld_lds16(const void* g, void* l) {
    __builtin_amdgcn_global_load_lds(
        (const __attribute__((address_space(1))) u32*)g,
        (__attribute__((address_space(3))) u32*)l, 16, 0, 0);
}

// ---------------------------------------------------------------------------
// prep_fused: one kernel for (a) x fp32->bf16, (b) w_qkv transpose-convert,
// (c) w_proj transpose-convert.  Partitioned by blockIdx range.
// ---------------------------------------------------------------------------
__global__ __launch_bounds__(256) void prep_fused(const float* __restrict__ x,
                                                  u16* __restrict__ xb,
                                                  const float* __restrict__ w_qkv,
                                                  u16* __restrict__ wqkvT,
                                                  const float* __restrict__ w_proj,
                                                  u16* __restrict__ wprojT) {
    __shared__ u16 tile[64][72];
    const int t = threadIdx.x;
    const int bid = blockIdx.x;
    if (bid < 2048) {
        const int n4 = (int)((size_t)B_ * HW_ * HD_ / 4);
        for (int i = bid * 256 + t; i < n4; i += 2048 * 256) {
            float4 v = ((const float4*)x)[i];
            ushort4 o;
            o.x = f2b(v.x); o.y = f2b(v.y); o.z = f2b(v.z); o.w = f2b(v.w);
            ((ushort4*)xb)[i] = o;
        }
        return;
    }
    int rem = bid - 2048;
    const float* in;
    u16* outp;
    int N, n0, k0;
    if (rem < 432) { in = w_qkv;  outp = wqkvT;  N = C3_; n0 = (rem % 36) * 64; k0 = (rem / 36) * 64; }
    else { rem -= 432; in = w_proj; outp = wprojT; N = C_;  n0 = (rem % 12) * 64; k0 = (rem / 12) * 64; }
    const int r = t >> 2, c4 = (t & 3) * 16;
    #pragma unroll
    for (int u = 0; u < 4; ++u) {
        float4 v = *(const float4*)(in + (size_t)(k0 + r) * N + n0 + c4 + u * 4);
        tile[c4 + u*4 + 0][r] = f2b(v.x);
        tile[c4 + u*4 + 1][r] = f2b(v.y);
        tile[c4 + u*4 + 2][r] = f2b(v.z);
        tile[c4 + u*4 + 3][r] = f2b(v.w);
    }
    __syncthreads();
    #pragma unroll
    for (int u = 0; u < 2; ++u) {
        s16x8 v;
        #pragma unroll
        for (int e = 0; e < 8; ++e) v[e] = (short)tile[r][c4 + u*8 + e];
        *(s16x8*)(outp + (size_t)(n0 + r) * 768 + k0 + c4 + u*8) = v;
    }
}

// ---------------------------------------------------------------------------
// GEMM core, 3-DEEP pipeline (r17-verified, 16x16x32 MFMA): 128x128 tile,
// BK=32, 4 waves 2x2.  Loads for tile kt+2 issued at iter kt; barrier waits
// vmcnt(4).  Raw s_barrier + lgkmcnt(0) + sched_barrier(0).  1D XCD swizzle.
// Dynamic LDS: 3x(8KB A + 8KB B) = 49152 B.  K = 768 (24 steps).
// ---------------------------------------------------------------------------
#define G3_ISSUE(KB, BUF)                                                            \
    gld_lds16(gA0 + (KB), sAb + (BUF) * 4096 + w * 512);                             \
    gld_lds16(gA1 + (KB), sAb + (BUF) * 4096 + (w + 4) * 512);                       \
    gld_lds16(gB0 + (KB), sBb + (BUF) * 4096 + w * 512);                             \
    gld_lds16(gB1 + (KB), sBb + (BUF) * 4096 + (w + 4) * 512);

#define G3_COMP(BUF)                                                                 \
    {                                                                                \
        const u16* pa = sAb + (BUF) * 4096 + (wm * 64 + l15) * 32 + lg * 8;          \
        const u16* pb = sBb + (BUF) * 4096 + (wn * 64 + l15) * 32 + lg * 8;          \
        s16x8 afr[4], bfr[4];                                                        \
        _Pragma("unroll")                                                            \
        for (int i = 0; i < 4; ++i) {                                                \
            afr[i] = *(const s16x8*)(pa + i * 512);                                  \
            bfr[i] = *(const s16x8*)(pb + i * 512);                                  \
        }                                                                            \
        _Pragma("unroll")                                                            \
        for (int i = 0; i < 4; ++i)                                                  \
            _Pragma("unroll")                                                        \
            for (int j = 0; j < 4; ++j)                                              \
                acc[i][j] = __builtin_amdgcn_mfma_f32_16x16x32_bf16(afr[i], bfr[j],  \
                                                                    acc[i][j], 0, 0, 0); \
    }

#define G3_BAR4                                                                      \
    asm volatile("s_waitcnt vmcnt(4) lgkmcnt(0)" ::: "memory");                      \
    __builtin_amdgcn_s_barrier();                                                    \
    __builtin_amdgcn_sched_barrier(0);

#define G3_BAR0                                                                      \
    asm volatile("s_waitcnt vmcnt(0) lgkmcnt(0)" ::: "memory");                      \
    __builtin_amdgcn_s_barrier();                                                    \
    __builtin_amdgcn_sched_barrier(0);

#define GEMM_CORE3(A_, Bt_, NT_)                                                     \
    extern __shared__ char smem[];                                                   \
    u16* sAb = (u16*)smem;                   /* 3 x [128*32] u16 */                  \
    u16* sBb = (u16*)(smem + 24576);         /* 3 x [128*32] u16 */                  \
    const int t = threadIdx.x;                                                       \
    const int lane = t & 63;                                                         \
    const int w = t >> 6;                                                            \
    const int wm = w >> 1, wn = w & 1;                                               \
    const int l15 = lane & 15, lg = lane >> 4;                                       \
    const int per = (int)gridDim.x >> 3;                                             \
    const int swz = ((int)blockIdx.x & 7) * per + ((int)blockIdx.x >> 3);            \
    const int nbase = (swz % (NT_)) * 128;                                           \
    const int mbase = (swz / (NT_)) * 128;                                           \
    const int srow = lane >> 2;                                                      \
    const int sslot = lane & 3;                                                      \
    const u16* gA0 = (A_) + (size_t)(mbase + w * 16 + srow) * 768 + sslot * 8;       \
    const u16* gA1 = gA0 + (size_t)64 * 768;                                         \
    const u16* gB0 = (Bt_) + (size_t)(nbase + w * 16 + srow) * 768 + sslot * 8;      \
    const u16* gB1 = gB0 + (size_t)64 * 768;                                         \
    f32x4 acc[4][4] = {};                                                            \
    G3_ISSUE(0, 0)                                                                   \
    G3_ISSUE(32, 1)                                                                  \
    G3_BAR4                                                                          \
    for (int k3 = 0; k3 < 7; ++k3) {                                                 \
        const int kb = k3 * 96;                                                      \
        G3_ISSUE(kb + 64, 2)  G3_COMP(0)  G3_BAR4                                    \
        G3_ISSUE(kb + 96, 0)  G3_COMP(1)  G3_BAR4                                    \
        G3_ISSUE(kb + 128, 1) G3_COMP(2)  G3_BAR4                                    \
    }                                                                                \
    G3_ISSUE(736, 2) G3_COMP(0) G3_BAR4                                              \
    G3_COMP(1) G3_BAR0                                                               \
    G3_COMP(2) G3_BAR0

// qkv = x @ w_qkv + b_qkv; bf16 q/k [b][p][64], v transposed [b][64][p];
// coalesced epilogue through LDS tile T[128][136].  (r17-verified; EF
// fusion reverted — it created a 1.5x tail on which==0 blocks, r20.)
__global__ __launch_bounds__(256) void gemm_qkv(const u16* __restrict__ A,
                                                const u16* __restrict__ Bt,
                                                const float* __restrict__ bias,
                                                u16* __restrict__ qout,
                                                u16* __restrict__ kout,
                                                u16* __restrict__ vout) {
    GEMM_CORE3(A, Bt, 18)
    u16* T = (u16*)smem;

    const int which = nbase / C_;
    const int head0 = (nbase % C_) >> 6;
    const int n_img = mbase >> 10;
    const int pbase = mbase & 1023;

    if (which < 2) {
        #pragma unroll
        for (int i = 0; i < 4; ++i)
            #pragma unroll
            for (int r = 0; r < 4; ++r) {
                const int lm = wm * 64 + i * 16 + lg * 4 + r;
                #pragma unroll
                for (int j = 0; j < 4; ++j) {
                    const int lc = wn * 64 + j * 16 + l15;
                    T[lm * 136 + lc] = f2b(acc[i][j][r] + bias[nbase + lc]);
                }
            }
    } else {
        #pragma unroll
        for (int i = 0; i < 4; ++i)
            #pragma unroll
            for (int r = 0; r < 4; ++r) {
                const int lm = wm * 64 + i * 16 + lg * 4 + r;
                #pragma unroll
                for (int j = 0; j < 4; ++j) {
                    const int lc = wn * 64 + j * 16 + l15;
                    T[lc * 136 + lm] = f2b(acc[i][j][r] + bias[nbase + lc]);
                }
            }
    }
    __syncthreads();

    if (which < 2) {
        u16* dst = (which == 0) ? qout : kout;
        #pragma unroll
        for (int pass = 0; pass < 4; ++pass) {
            const int lm = pass * 32 + (t >> 3);
            #pragma unroll
            for (int hh = 0; hh < 2; ++hh) {
                s16x8 row = *(const s16x8*)(T + lm * 136 + hh * 64 + (t & 7) * 8);
                const size_t bidx = (size_t)(n_img * NH_ + head0 + hh);
                *(s16x8*)(dst + (bidx * HW_ + pbase + lm) * HD_ + (t & 7) * 8) = row;
            }
        }
    } else {
        #pragma unroll
        for (int pass = 0; pass < 8; ++pass) {
            const int lc = pass * 16 + (t >> 4);
            s16x8 row = *(const s16x8*)(T + lc * 136 + (t & 15) * 8);
            const int hh = lc >> 6, d = lc & 63;
            const size_t bidx = (size_t)(n_img * NH_ + head0 + hh);
            *(s16x8*)(vout + bidx * (size_t)(HW_ * HD_) + (size_t)d * HW_ + pbase + (t & 15) * 8) = row;
        }
    }
}

// out = o @ w_proj + b_proj, fp32 out (r17-verified)
__global__ __launch_bounds__(256) void gemm_proj(const u16* __restrict__ A,
                                                 const u16* __restrict__ Bt,
                                                 const float* __restrict__ bias,
                                                 float* __restrict__ out) {
    GEMM_CORE3(A, Bt, 6)
    const int mrow0 = mbase + wm * 64 + lg * 4;
    #pragma unroll
    for (int i = 0; i < 4; ++i) {
        #pragma unroll
        for (int r = 0; r < 4; ++r) {
            const int m = mrow0 + i * 16 + r;
            #pragma unroll
            for (int j = 0; j < 4; ++j) {
                const int n = nbase + wn * 64 + j * 16 + l15;
                out[(size_t)m * C_ + n] = acc[i][j][r] + bias[n];
            }
        }
    }
}

// ---------------------------------------------------------------------------
// ef_gemm: F = Q @ rel_h^T, E = Q @ rel_w^T (x LOG2E), bf16 out [98304][64].
//   bias_h[q][kh] = F[q][(q>>5)+31-kh],  bias_w[q][kw] = E[q][(q&31)+31-kw].
// (r17-verified standalone form; q read from global bf16, L2-hot post-qkv.)
// ---------------------------------------------------------------------------
__global__ __launch_bounds__(256) void ef_gemm(const u16* __restrict__ qb_,
                                               const float* __restrict__ rel_h,
                                               const float* __restrict__ rel_w,
                                               u16* __restrict__ Fg,
                                               u16* __restrict__ Eg) {
    const int t = threadIdx.x;
    const int lane = t & 63;
    const int w = t >> 6;
    const int l31 = lane & 31;
    const int hi  = lane >> 5;
    const size_t Mrow = (size_t)blockIdx.x * 128 + w * 32 + l31;

    s16x8 qb[4];
    {
        const u16* qrow = qb_ + Mrow * HD_;
        #pragma unroll
        for (int ck = 0; ck < 4; ++ck)
            qb[ck] = *(const s16x8*)(qrow + ck * 16 + hi * 8);
    }

    #pragma unroll
    for (int tb = 0; tb < 2; ++tb) {
        const float* R = tb ? rel_w : rel_h;
        u16* og = (tb ? Eg : Fg) + Mrow * 64;
        #pragma unroll
        for (int hh = 0; hh < 2; ++hh) {
            const int dr = hh * 32 + l31;
            const float* rrow = R + (size_t)(dr > 62 ? 62 : dr) * HD_;
            f32x16 acc = {};
            #pragma unroll
            for (int ck = 0; ck < 4; ++ck) {
                float4 r0 = *(const float4*)(rrow + ck * 16 + hi * 8);
                float4 r1 = *(const float4*)(rrow + ck * 16 + hi * 8 + 4);
                s16x8 af;
                af[0] = (short)f2b(r0.x * LOG2E_); af[1] = (short)f2b(r0.y * LOG2E_);
                af[2] = (short)f2b(r0.z * LOG2E_); af[3] = (short)f2b(r0.w * LOG2E_);
                af[4] = (short)f2b(r1.x * LOG2E_); af[5] = (short)f2b(r1.y * LOG2E_);
                af[6] = (short)f2b(r1.z * LOG2E_); af[7] = (short)f2b(r1.w * LOG2E_);
                acc = __builtin_amdgcn_mfma_f32_32x32x16_bf16(af, qb[ck], acc, 0, 0, 0);
            }
            #pragma unroll
            for (int u = 0; u < 4; ++u) {
                u32x2 pkd;
                pkd.x = cvtpk(acc[4*u+0], acc[4*u+1]);
                pkd.y = cvtpk(acc[4*u+2], acc[4*u+3]);
                *(u32x2*)(og + hh * 32 + u * 8 + 4 * hi) = pkd;
            }
        }
    }
}

// ---------------------------------------------------------------------------
// attn — unchanged from round 17 (dbuf + raw barrier + E/F tables + setprio
// + cvt_pk P pack + MFMA row-sum).
// ---------------------------------------------------------------------------
__global__ __launch_bounds__(256) void attn_mfma(const u16* __restrict__ qb_,
                                                 const u16* __restrict__ kbf,
                                                 const u16* __restrict__ vtb,
                                                 const u16* __restrict__ Fg,
                                                 const u16* __restrict__ Eg,
                                                 u16* __restrict__ ob) {
    extern __shared__ char smem[];
    u16*   sBH  = (u16*)smem;
    u16*   sK0  = (u16*)(smem + 8704);
    u16*   sK1  = (u16*)(smem + 17920);
    u16*   sVt0 = (u16*)(smem + 27136);
    u16*   sVt1 = (u16*)(smem + 36352);

    const int t = threadIdx.x;
    const int lane = t & 63;
    const int w = t >> 6;
    const int l31 = lane & 31;
    const int hi  = lane >> 5;
    const int qw  = w * 32;

    const int bid = blockIdx.x;
    const int swz = (bid & 7) * 96 + (bid >> 3);
    const int b = swz >> 3;
    const int qbase = (swz & 7) * 128;

    s16x8 qfr[4];
    {
        const u16* qrow = qb_ + ((size_t)b * HW_ + qbase + qw + l31) * HD_;
        #pragma unroll
        for (int ck = 0; ck < 4; ++ck) {
            s16x8 qv = *(const s16x8*)(qrow + ck * 16 + hi * 8);
            #pragma unroll
            for (int e = 0; e < 8; ++e)
                qfr[ck][e] = (short)f2b(b2f((u16)qv[e]) * (SCALE_ * LOG2E_));
        }
    }

    {
        const u16* Fb = Fg + (size_t)b * HW_ * 64;
        for (int idv = t; idv < 4096; idv += 256) {
            const int row = idv >> 5;
            const int kh  = idv & 31;
            const int qg  = qbase + row;
            sBH[row * 34 + kh] = Fb[(size_t)qg * 64 + (qg >> 5) + 31 - kh];
        }
    }

    f32x4 bwv[4];
    {
        const int qmy = qbase + qw + l31;
        const u16* Erow = Eg + (size_t)(b * HW_ + qmy) * 64;
        #pragma unroll
        for (int m = 0; m < 4; ++m)
            #pragma unroll
            for (int j = 0; j < 4; ++j)
                bwv[m][j] = b2f(Erow[l31 + 31 - (m * 8 + 4 * hi + j)]);
    }

    const int srow = t >> 2;
    const int sc0  = (t & 3) * 16;
    const u16* kg = kbf + ((size_t)b * HW_ + srow) * HD_ + sc0;
    const u16* vg = vtb + (size_t)b * HD_ * HW_ + (size_t)srow * HW_ + sc0;
    u16* skw0 = sK0  + srow * 72 + sc0;
    u16* skw1 = sK1  + srow * 72 + sc0;
    u16* svw0 = sVt0 + srow * 72 + sc0;
    u16* svw1 = sVt1 + srow * 72 + sc0;

    s16x8 kr0 = *(const s16x8*)(kg);
    s16x8 kr1 = *(const s16x8*)(kg + 8);
    s16x8 vr0 = *(const s16x8*)(vg);
    s16x8 vr1 = *(const s16x8*)(vg + 8);
    *(s16x8*)(skw0)     = kr0;
    *(s16x8*)(skw0 + 8) = kr1;
    *(s16x8*)(svw0)     = vr0;
    *(s16x8*)(svw0 + 8) = vr1;
    __syncthreads();

    f32x16 Oacc[2] = {};
    f32x16 Osum = {};
    const u32x4 onesu = {0x3F803F80u, 0x3F803F80u, 0x3F803F80u, 0x3F803F80u};
    const s16x8 ones = *reinterpret_cast<const s16x8*>(&onesu);
    const int bhbase = (qw + l31) * 34;

    auto body = [&](int kt, const u16* sKr, const u16* sVr, u16* skwN, u16* svwN) {
        if (kt < 15) {
            const u16* kn = kg + (size_t)(kt + 1) * 64 * HD_;
            kr0 = *(const s16x8*)(kn);
            kr1 = *(const s16x8*)(kn + 8);
            const u16* vn = vg + (size_t)(kt + 1) * 64;
            vr0 = *(const s16x8*)(vn);
            vr1 = *(const s16x8*)(vn + 8);
        }

        const float bh0 = b2f(sBH[bhbase + 2 * kt]);
        const float bh1 = b2f(sBH[bhbase + 2 * kt + 1]);

        #pragma unroll
        for (int kvt = 0; kvt < 2; ++kvt) {
            f32x16 s = {};
            __builtin_amdgcn_s_setprio(1);
            #pragma unroll
            for (int ck = 0; ck < 4; ++ck) {
                s16x8 kf = *(const s16x8*)(sKr + (kvt * 32 + l31) * 72 + ck * 16 + hi * 8);
                s = __builtin_amdgcn_mfma_f32_32x32x16_bf16(kf, qfr[ck], s, 0, 0, 0);
            }
            __builtin_amdgcn_s_setprio(0);
            const float bh = kvt ? bh1 : bh0;

            u32 pw[8];
            #pragma unroll
            for (int m = 0; m < 8; ++m) {
                float p0 = __builtin_amdgcn_exp2f(s[2*m]   + bh + bwv[(2*m)>>2][(2*m)&3]);
                float p1 = __builtin_amdgcn_exp2f(s[2*m+1] + bh + bwv[(2*m+1)>>2][(2*m+1)&3]);
                pw[m] = cvtpk(p0, p1);
            }

            __builtin_amdgcn_s_setprio(1);
            #pragma unroll
            for (int cc = 0; cc < 2; ++cc) {
                i32x2 s02 = __builtin_amdgcn_permlane32_swap((int)pw[cc*4+0], (int)pw[cc*4+2], false, false);
                i32x2 s13 = __builtin_amdgcn_permlane32_swap((int)pw[cc*4+1], (int)pw[cc*4+3], false, false);
                u32x4 pau;
                pau.x = (u32)s02.x; pau.y = (u32)s13.x;
                pau.z = (u32)s02.y; pau.w = (u32)s13.y;
                s16x8 pa = *reinterpret_cast<s16x8*>(&pau);
                const int kc = kvt * 2 + cc;
                #pragma unroll
                for (int dt = 0; dt < 2; ++dt) {
                    s16x8 vf = *(const s16x8*)(sVr + (dt * 32 + l31) * 72 + kc * 16 + hi * 8);
                    Oacc[dt] = __builtin_amdgcn_mfma_f32_32x32x16_bf16(pa, vf, Oacc[dt], 0, 0, 0);
                }
                Osum = __builtin_amdgcn_mfma_f32_32x32x16_bf16(pa, ones, Osum, 0, 0, 0);
            }
            __builtin_amdgcn_s_setprio(0);
        }

        if (kt < 15) {
            *(s16x8*)(skwN)     = kr0;
            *(s16x8*)(skwN + 8) = kr1;
            *(s16x8*)(svwN)     = vr0;
            *(s16x8*)(svwN + 8) = vr1;
        }
        asm volatile("s_waitcnt lgkmcnt(0)" ::: "memory");
        __builtin_amdgcn_s_barrier();
        __builtin_amdgcn_sched_barrier(0);
    };

    for (int k2 = 0; k2 < 8; ++k2) {
        body(2 * k2,     sK0, sVt0, skw1, svw1);
        body(2 * k2 + 1, sK1, sVt1, skw0, svw0);
    }

    const int n_img = b / NH_;
    const int head  = b % NH_;
    #pragma unroll
    for (int dt = 0; dt < 2; ++dt) {
        #pragma unroll
        for (int r = 0; r < 16; ++r) {
            const int qloc = (r & 3) + 8 * (r >> 2) + 4 * hi;
            const int qg = qbase + qw + qloc;
            ob[(size_t)(n_img * HW_ + qg) * C_ + head * HD_ + dt * 32 + l31] =
                f2b(Oacc[dt][r] / Osum[r]);
        }
    }
}

extern "C" void kernel_launch(void* const* d_in, const int* in_sizes, int n_in,
                              void* d_out, int out_size, void* d_ws, size_t ws_size,
                              hipStream_t stream) {
    const float* x      = (const float*)d_in[0];
    const float* w_qkv  = (const float*)d_in[1];
    const float* b_qkv  = (const float*)d_in[2];
    const float* w_proj = (const float*)d_in[3];
    const float* b_proj = (const float*)d_in[4];
    const float* rel_h  = (const float*)d_in[5];
    const float* rel_w  = (const float*)d_in[6];
    float* out = (float*)d_out;

    const size_t seg = (size_t)B_ * HW_ * HD_;   // 6,291,456
    char* p = (char*)d_ws;
    u16* xb     = (u16*)p;  p += seg * 2;
    u16* wqkvT  = (u16*)p;  p += (size_t)C3_ * C_ * 2;
    u16* wprojT = (u16*)p;  p += (size_t)C_ * C_ * 2;
    u16* qb     = (u16*)p;  p += seg * 2;
    u16* kbf    = (u16*)p;  p += seg * 2;
    u16* vtb    = (u16*)p;  p += seg * 2;
    u16* ob     = (u16*)p;  p += seg * 2;
    u16* Fg     = (u16*)p;  p += seg * 2;
    u16* Eg     = (u16*)p;  p += seg * 2;

    prep_fused<<<2624, 256, 0, stream>>>(x, xb, w_qkv, wqkvT, w_proj, wprojT);
    gemm_qkv<<<1152, 256, 49152, stream>>>(xb, wqkvT, b_qkv, qb, kbf, vtb);
    ef_gemm<<<768, 256, 0, stream>>>(qb, rel_h, rel_w, Fg, Eg);
    attn_mfma<<<768, 256, 45568, stream>>>(qb, kbf, vtb, Fg, Eg, ob);
    gemm_proj<<<384, 256, 49152, stream>>>(ob, wprojT, b_proj, out);
}

// Round 23
// 137.766 us; speedup vs baseline: 1.0572x; 1.0006x over previous
//
#include <hip/hip_runtime.h>
#include <hip/hip_bf16.h>

#define N_    8
#define H_    32
#define W_    32
#define C_    768
#define NH_   12
#define HD_   64
#define B_    96      // N_*NH_
#define HW_   1024
#define C3_   2304
#define SCALE_ 0.125f
#define LOG2E_ 1.4426950408889634f

typedef __attribute__((ext_vector_type(4))) float f32x4;
typedef __attribute__((ext_vector_type(16))) float f32x16;
typedef __attribute__((ext_vector_type(8))) short s16x8;
typedef __attribute__((ext_vector_type(2))) int i32x2;
typedef __attribute__((ext_vector_type(2))) unsigned int u32x2;
typedef __attribute__((ext_vector_type(4))) unsigned int u32x4;
typedef unsigned short u16;
typedef unsigned int u32;

__device__ inline u16 f2b(float x) {
    __hip_bfloat16 h = __float2bfloat16(x);
    return *reinterpret_cast<u16*>(&h);
}
__device__ inline float b2f(u16 x) {
    u32 u = ((u32)x) << 16;
    return *reinterpret_cast<float*>(&u);
}
__device__ __forceinline__ u32 cvtpk(float a, float b) {
    u32 r;
    asm("v_cvt_pk_bf16_f32 %0, %1, %2" : "=v"(r) : "v"(a), "v"(b));
    return r;
}

__device__ __forceinline__ void gld_lds16(const void* g, void* l) {
    __builtin_amdgcn_global_load_lds(
        (const __attribute__((address_space(1))) u32*)g,
        (__attribute__((address_space(3))) u32*)l, 16, 0, 0);
}

// ---------------------------------------------------------------------------
// prep_fused: one kernel for (a) x fp32->bf16, (b) w_qkv transpose-convert,
// (c) w_proj transpose-convert.  Partitioned by blockIdx range.
// ---------------------------------------------------------------------------
__global__ __launch_bounds__(256) void prep_fused(const float* __restrict__ x,
                                                  u16* __restrict__ xb,
                                                  const float* __restrict__ w_qkv,
                                                  u16* __restrict__ wqkvT,
                                                  const float* __restrict__ w_proj,
                                                  u16* __restrict__ wprojT) {
    __shared__ u16 tile[64][72];
    const int t = threadIdx.x;
    const int bid = blockIdx.x;
    if (bid < 2048) {
        const int n4 = (int)((size_t)B_ * HW_ * HD_ / 4);
        for (int i = bid * 256 + t; i < n4; i += 2048 * 256) {
            float4 v = ((const float4*)x)[i];
            ushort4 o;
            o.x = f2b(v.x); o.y = f2b(v.y); o.z = f2b(v.z); o.w = f2b(v.w);
            ((ushort4*)xb)[i] = o;
        }
        return;
    }
    int rem = bid - 2048;
    const float* in;
    u16* outp;
    int N, n0, k0;
    if (rem < 432) { in = w_qkv;  outp = wqkvT;  N = C3_; n0 = (rem % 36) * 64; k0 = (rem / 36) * 64; }
    else { rem -= 432; in = w_proj; outp = wprojT; N = C_;  n0 = (rem % 12) * 64; k0 = (rem / 12) * 64; }
    const int r = t >> 2, c4 = (t & 3) * 16;
    #pragma unroll
    for (int u = 0; u < 4; ++u) {
        float4 v = *(const float4*)(in + (size_t)(k0 + r) * N + n0 + c4 + u * 4);
        tile[c4 + u*4 + 0][r] = f2b(v.x);
        tile[c4 + u*4 + 1][r] = f2b(v.y);
        tile[c4 + u*4 + 2][r] = f2b(v.z);
        tile[c4 + u*4 + 3][r] = f2b(v.w);
    }
    __syncthreads();
    #pragma unroll
    for (int u = 0; u < 2; ++u) {
        s16x8 v;
        #pragma unroll
        for (int e = 0; e < 8; ++e) v[e] = (short)tile[r][c4 + u*8 + e];
        *(s16x8*)(outp + (size_t)(n0 + r) * 768 + k0 + c4 + u*8) = v;
    }
}

// ---------------------------------------------------------------------------
// GEMM core, 3-DEEP pipeline (r17-verified, 16x16x32 MFMA): 128x128 tile,
// BK=32, 4 waves 2x2.  Loads for tile kt+2 issued at iter kt; barrier waits
// vmcnt(4).  Raw s_barrier + lgkmcnt(0) + sched_barrier(0).  1D XCD swizzle.
// Dynamic LDS: 3x(8KB A + 8KB B) = 49152 B.  K = 768 (24 steps).
// ---------------------------------------------------------------------------
#define G3_ISSUE(KB, BUF)                                                            \
    gld_lds16(gA0 + (KB), sAb + (BUF) * 4096 + w * 512);                             \
    gld_lds16(gA1 + (KB), sAb + (BUF) * 4096 + (w + 4) * 512);                       \
    gld_lds16(gB0 + (KB), sBb + (BUF) * 4096 + w * 512);                             \
    gld_lds16(gB1 + (KB), sBb + (BUF) * 4096 + (w + 4) * 512);

#define G3_COMP(BUF)                                                                 \
    {                                                                                \
        const u16* pa = sAb + (BUF) * 4096 + (wm * 64 + l15) * 32 + lg * 8;          \
        const u16* pb = sBb + (BUF) * 4096 + (wn * 64 + l15) * 32 + lg * 8;          \
        s16x8 afr[4], bfr[4];                                                        \
        _Pragma("unroll")                                                            \
        for (int i = 0; i < 4; ++i) {                                                \
            afr[i] = *(const s16x8*)(pa + i * 512);                                  \
            bfr[i] = *(const s16x8*)(pb + i * 512);                                  \
        }                                                                            \
        _Pragma("unroll")                                                            \
        for (int i = 0; i < 4; ++i)                                                  \
            _Pragma("unroll")                                                        \
            for (int j = 0; j < 4; ++j)                                              \
                acc[i][j] = __builtin_amdgcn_mfma_f32_16x16x32_bf16(afr[i], bfr[j],  \
                                                                    acc[i][j], 0, 0, 0); \
    }

#define G3_BAR4                                                                      \
    asm volatile("s_waitcnt vmcnt(4) lgkmcnt(0)" ::: "memory");                      \
    __builtin_amdgcn_s_barrier();                                                    \
    __builtin_amdgcn_sched_barrier(0);

#define G3_BAR0                                                                      \
    asm volatile("s_waitcnt vmcnt(0) lgkmcnt(0)" ::: "memory");                      \
    __builtin_amdgcn_s_barrier();                                                    \
    __builtin_amdgcn_sched_barrier(0);

#define GEMM_CORE3(A_, Bt_, NT_)                                                     \
    extern __shared__ char smem[];                                                   \
    u16* sAb = (u16*)smem;                   /* 3 x [128*32] u16 */                  \
    u16* sBb = (u16*)(smem + 24576);         /* 3 x [128*32] u16 */                  \
    const int t = threadIdx.x;                                                       \
    const int lane = t & 63;                                                         \
    const int w = t >> 6;                                                            \
    const int wm = w >> 1, wn = w & 1;                                               \
    const int l15 = lane & 15, lg = lane >> 4;                                       \
    const int per = (int)gridDim.x >> 3;                                             \
    const int swz = ((int)blockIdx.x & 7) * per + ((int)blockIdx.x >> 3);            \
    const int nbase = (swz % (NT_)) * 128;                                           \
    const int mbase = (swz / (NT_)) * 128;                                           \
    const int srow = lane >> 2;                                                      \
    const int sslot = lane & 3;                                                      \
    const u16* gA0 = (A_) + (size_t)(mbase + w * 16 + srow) * 768 + sslot * 8;       \
    const u16* gA1 = gA0 + (size_t)64 * 768;                                         \
    const u16* gB0 = (Bt_) + (size_t)(nbase + w * 16 + srow) * 768 + sslot * 8;      \
    const u16* gB1 = gB0 + (size_t)64 * 768;                                         \
    f32x4 acc[4][4] = {};                                                            \
    G3_ISSUE(0, 0)                                                                   \
    G3_ISSUE(32, 1)                                                                  \
    G3_BAR4                                                                          \
    for (int k3 = 0; k3 < 7; ++k3) {                                                 \
        const int kb = k3 * 96;                                                      \
        G3_ISSUE(kb + 64, 2)  G3_COMP(0)  G3_BAR4                                    \
        G3_ISSUE(kb + 96, 0)  G3_COMP(1)  G3_BAR4                                    \
        G3_ISSUE(kb + 128, 1) G3_COMP(2)  G3_BAR4                                    \
    }                                                                                \
    G3_ISSUE(736, 2) G3_COMP(0) G3_BAR4                                              \
    G3_COMP(1) G3_BAR0                                                               \
    G3_COMP(2) G3_BAR0

// qkv = x @ w_qkv + b_qkv; bf16 q/k [b][p][64], v transposed [b][64][p];
// coalesced epilogue through LDS tile T[128][136].  (r17-verified)
__global__ __launch_bounds__(256) void gemm_qkv(const u16* __restrict__ A,
                                                const u16* __restrict__ Bt,
                                                const float* __restrict__ bias,
                                                u16* __restrict__ qout,
                                                u16* __restrict__ kout,
                                                u16* __restrict__ vout) {
    GEMM_CORE3(A, Bt, 18)
    u16* T = (u16*)smem;

    const int which = nbase / C_;
    const int head0 = (nbase % C_) >> 6;
    const int n_img = mbase >> 10;
    const int pbase = mbase & 1023;

    if (which < 2) {
        #pragma unroll
        for (int i = 0; i < 4; ++i)
            #pragma unroll
            for (int r = 0; r < 4; ++r) {
                const int lm = wm * 64 + i * 16 + lg * 4 + r;
                #pragma unroll
                for (int j = 0; j < 4; ++j) {
                    const int lc = wn * 64 + j * 16 + l15;
                    T[lm * 136 + lc] = f2b(acc[i][j][r] + bias[nbase + lc]);
                }
            }
    } else {
        #pragma unroll
        for (int i = 0; i < 4; ++i)
            #pragma unroll
            for (int r = 0; r < 4; ++r) {
                const int lm = wm * 64 + i * 16 + lg * 4 + r;
                #pragma unroll
                for (int j = 0; j < 4; ++j) {
                    const int lc = wn * 64 + j * 16 + l15;
                    T[lc * 136 + lm] = f2b(acc[i][j][r] + bias[nbase + lc]);
                }
            }
    }
    __syncthreads();

    if (which < 2) {
        u16* dst = (which == 0) ? qout : kout;
        #pragma unroll
        for (int pass = 0; pass < 4; ++pass) {
            const int lm = pass * 32 + (t >> 3);
            #pragma unroll
            for (int hh = 0; hh < 2; ++hh) {
                s16x8 row = *(const s16x8*)(T + lm * 136 + hh * 64 + (t & 7) * 8);
                const size_t bidx = (size_t)(n_img * NH_ + head0 + hh);
                *(s16x8*)(dst + (bidx * HW_ + pbase + lm) * HD_ + (t & 7) * 8) = row;
            }
        }
    } else {
        #pragma unroll
        for (int pass = 0; pass < 8; ++pass) {
            const int lc = pass * 16 + (t >> 4);
            s16x8 row = *(const s16x8*)(T + lc * 136 + (t & 15) * 8);
            const int hh = lc >> 6, d = lc & 63;
            const size_t bidx = (size_t)(n_img * NH_ + head0 + hh);
            *(s16x8*)(vout + bidx * (size_t)(HW_ * HD_) + (size_t)d * HW_ + pbase + (t & 15) * 8) = row;
        }
    }
}

// out = o @ w_proj + b_proj, fp32 out (r17-verified)
__global__ __launch_bounds__(256) void gemm_proj(const u16* __restrict__ A,
                                                 const u16* __restrict__ Bt,
                                                 const float* __restrict__ bias,
                                                 float* __restrict__ out) {
    GEMM_CORE3(A, Bt, 6)
    const int mrow0 = mbase + wm * 64 + lg * 4;
    #pragma unroll
    for (int i = 0; i < 4; ++i) {
        #pragma unroll
        for (int r = 0; r < 4; ++r) {
            const int m = mrow0 + i * 16 + r;
            #pragma unroll
            for (int j = 0; j < 4; ++j) {
                const int n = nbase + wn * 64 + j * 16 + l15;
                out[(size_t)m * C_ + n] = acc[i][j][r] + bias[n];
            }
        }
    }
}

// ---------------------------------------------------------------------------
// ef_gemm: F = Q @ rel_h^T, E = Q @ rel_w^T (x LOG2E), bf16 out [98304][64].
//   bias_h[q][kh] = F[q][(q>>5)+31-kh],  bias_w[q][kw] = E[q][(q&31)+31-kw].
// (r17-verified standalone form; q read from global bf16, L2-hot post-qkv.)
// ---------------------------------------------------------------------------
__global__ __launch_bounds__(256) void ef_gemm(const u16* __restrict__ qb_,
                                               const float* __restrict__ rel_h,
                                               const float* __restrict__ rel_w,
                                               u16* __restrict__ Fg,
                                               u16* __restrict__ Eg) {
    const int t = threadIdx.x;
    const int lane = t & 63;
    const int w = t >> 6;
    const int l31 = lane & 31;
    const int hi  = lane >> 5;
    const size_t Mrow = (size_t)blockIdx.x * 128 + w * 32 + l31;

    s16x8 qb[4];
    {
        const u16* qrow = qb_ + Mrow * HD_;
        #pragma unroll
        for (int ck = 0; ck < 4; ++ck)
            qb[ck] = *(const s16x8*)(qrow + ck * 16 + hi * 8);
    }

    #pragma unroll
    for (int tb = 0; tb < 2; ++tb) {
        const float* R = tb ? rel_w : rel_h;
        u16* og = (tb ? Eg : Fg) + Mrow * 64;
        #pragma unroll
        for (int hh = 0; hh < 2; ++hh) {
            const int dr = hh * 32 + l31;
            const float* rrow = R + (size_t)(dr > 62 ? 62 : dr) * HD_;
            f32x16 acc = {};
            #pragma unroll
            for (int ck = 0; ck < 4; ++ck) {
                float4 r0 = *(const float4*)(rrow + ck * 16 + hi * 8);
                float4 r1 = *(const float4*)(rrow + ck * 16 + hi * 8 + 4);
                s16x8 af;
                af[0] = (short)f2b(r0.x * LOG2E_); af[1] = (short)f2b(r0.y * LOG2E_);
                af[2] = (short)f2b(r0.z * LOG2E_); af[3] = (short)f2b(r0.w * LOG2E_);
                af[4] = (short)f2b(r1.x * LOG2E_); af[5] = (short)f2b(r1.y * LOG2E_);
                af[6] = (short)f2b(r1.z * LOG2E_); af[7] = (short)f2b(r1.w * LOG2E_);
                acc = __builtin_amdgcn_mfma_f32_32x32x16_bf16(af, qb[ck], acc, 0, 0, 0);
            }
            #pragma unroll
            for (int u = 0; u < 4; ++u) {
                u32x2 pkd;
                pkd.x = cvtpk(acc[4*u+0], acc[4*u+1]);
                pkd.y = cvtpk(acc[4*u+2], acc[4*u+3]);
                *(u32x2*)(og + hh * 32 + u * 8 + 4 * hi) = pkd;
            }
        }
    }
}

// ---------------------------------------------------------------------------
// attn — r17/r21 main loop (dbuf + raw barrier + E/F tables + setprio +
// cvt_pk P pack + MFMA row-sum).
// ---------------------------------------------------------------------------
__global__ __launch_bounds__(256) void attn_mfma(const u16* __restrict__ qb_,
                                                 const u16* __restrict__ kbf,
                                                 const u16* __restrict__ vtb,
                                                 const u16* __restrict__ Fg,
                                                 const u16* __restrict__ Eg,
                                                 u16* __restrict__ ob) {
    extern __shared__ char smem[];
    u16*   sBH  = (u16*)smem;
    u16*   sK0  = (u16*)(smem + 8704);
    u16*   sK1  = (u16*)(smem + 17920);
    u16*   sVt0 = (u16*)(smem + 27136);
    u16*   sVt1 = (u16*)(smem + 36352);

    const int t = threadIdx.x;
    const int lane = t & 63;
    const int w = t >> 6;
    const int l31 = lane & 31;
    const int hi  = lane >> 5;
    const int qw  = w * 32;

    const int bid = blockIdx.x;
    const int swz = (bid & 7) * 96 + (bid >> 3);
    const int b = swz >> 3;
    const int qbase = (swz & 7) * 128;

    s16x8 qfr[4];
    {
        const u16* qrow = qb_ + ((size_t)b * HW_ + qbase + qw + l31) * HD_;
        #pragma unroll
        for (int ck = 0; ck < 4; ++ck) {
            s16x8 qv = *(const s16x8*)(qrow + ck * 16 + hi * 8);
            #pragma unroll
            for (int e = 0; e < 8; ++e)
                qfr[ck][e] = (short)f2b(b2f((u16)qv[e]) * (SCALE_ * LOG2E_));
        }
    }

    {
        const u16* Fb = Fg + (size_t)b * HW_ * 64;
        for (int idv = t; idv < 4096; idv += 256) {
            const int row = idv >> 5;
            const int kh  = idv & 31;
            const int qg  = qbase + row;
            sBH[row * 34 + kh] = Fb[(size_t)qg * 64 + (qg >> 5) + 31 - kh];
        }
    }

    f32x4 bwv[4];
    {
        const int qmy = qbase + qw + l31;
        const u16* Erow = Eg + (size_t)(b * HW_ + qmy) * 64;
        #pragma unroll
        for (int m = 0; m < 4; ++m)
            #pragma unroll
            for (int j = 0; j < 4; ++j)
                bwv[m][j] = b2f(Erow[l31 + 31 - (m * 8 + 4 * hi + j)]);
    }

    const int srow = t >> 2;
    const int sc0  = (t & 3) * 16;
    const u16* kg = kbf + ((size_t)b * HW_ + srow) * HD_ + sc0;
    const u16* vg = vtb + (size_t)b * HD_ * HW_ + (size_t)srow * HW_ + sc0;
    u16* skw0 = sK0  + srow * 72 + sc0;
    u16* skw1 = sK1  + srow * 72 + sc0;
    u16* svw0 = sVt0 + srow * 72 + sc0;
    u16* svw1 = sVt1 + srow * 72 + sc0;

    s16x8 kr0 = *(const s16x8*)(kg);
    s16x8 kr1 = *(const s16x8*)(kg + 8);
    s16x8 vr0 = *(const s16x8*)(vg);
    s16x8 vr1 = *(const s16x8*)(vg + 8);
    *(s16x8*)(skw0)     = kr0;
    *(s16x8*)(skw0 + 8) = kr1;
    *(s16x8*)(svw0)     = vr0;
    *(s16x8*)(svw0 + 8) = vr1;
    __syncthreads();

    f32x16 Oacc[2] = {};
    f32x16 Osum = {};
    const u32x4 onesu = {0x3F803F80u, 0x3F803F80u, 0x3F803F80u, 0x3F803F80u};
    const s16x8 ones = *reinterpret_cast<const s16x8*>(&onesu);
    const int bhbase = (qw + l31) * 34;

    auto body = [&](int kt, const u16* sKr, const u16* sVr, u16* skwN, u16* svwN) {
        if (kt < 15) {
            const u16* kn = kg + (size_t)(kt + 1) * 64 * HD_;
            kr0 = *(const s16x8*)(kn);
            kr1 = *(const s16x8*)(kn + 8);
            const u16* vn = vg + (size_t)(kt + 1) * 64;
            vr0 = *(const s16x8*)(vn);
            vr1 = *(const s16x8*)(vn + 8);
        }

        const float bh0 = b2f(sBH[bhbase + 2 * kt]);
        const float bh1 = b2f(sBH[bhbase + 2 * kt + 1]);

        #pragma unroll
        for (int kvt = 0; kvt < 2; ++kvt) {
            f32x16 s = {};
            __builtin_amdgcn_s_setprio(1);
            #pragma unroll
            for (int ck = 0; ck < 4; ++ck) {
                s16x8 kf = *(const s16x8*)(sKr + (kvt * 32 + l31) * 72 + ck * 16 + hi * 8);
                s = __builtin_amdgcn_mfma_f32_32x32x16_bf16(kf, qfr[ck], s, 0, 0, 0);
            }
            __builtin_amdgcn_s_setprio(0);
            const float bh = kvt ? bh1 : bh0;

            u32 pw[8];
            #pragma unroll
            for (int m = 0; m < 8; ++m) {
                float p0 = __builtin_amdgcn_exp2f(s[2*m]   + bh + bwv[(2*m)>>2][(2*m)&3]);
                float p1 = __builtin_amdgcn_exp2f(s[2*m+1] + bh + bwv[(2*m+1)>>2][(2*m+1)&3]);
                pw[m] = cvtpk(p0, p1);
            }

            __builtin_amdgcn_s_setprio(1);
            #pragma unroll
            for (int cc = 0; cc < 2; ++cc) {
                i32x2 s02 = __builtin_amdgcn_permlane32_swap((int)pw[cc*4+0], (int)pw[cc*4+2], false, false);
                i32x2 s13 = __builtin_amdgcn_permlane32_swap((int)pw[cc*4+1], (int)pw[cc*4+3], false, false);
                u32x4 pau;
                pau.x = (u32)s02.x; pau.y = (u32)s13.x;
                pau.z = (u32)s02.y; pau.w = (u32)s13.y;
                s16x8 pa = *reinterpret_cast<s16x8*>(&pau);
                const int kc = kvt * 2 + cc;
                #pragma unroll
                for (int dt = 0; dt < 2; ++dt) {
                    s16x8 vf = *(const s16x8*)(sVr + (dt * 32 + l31) * 72 + kc * 16 + hi * 8);
                    Oacc[dt] = __builtin_amdgcn_mfma_f32_32x32x16_bf16(pa, vf, Oacc[dt], 0, 0, 0);
                }
                Osum = __builtin_amdgcn_mfma_f32_32x32x16_bf16(pa, ones, Osum, 0, 0, 0);
            }
            __builtin_amdgcn_s_setprio(0);
        }

        if (kt < 15) {
            *(s16x8*)(skwN)     = kr0;
            *(s16x8*)(skwN + 8) = kr1;
            *(s16x8*)(svwN)     = vr0;
            *(s16x8*)(svwN + 8) = vr1;
        }
        asm volatile("s_waitcnt lgkmcnt(0)" ::: "memory");
        __builtin_amdgcn_s_barrier();
        __builtin_amdgcn_sched_barrier(0);
    };

    for (int k2 = 0; k2 < 8; ++k2) {
        body(2 * k2,     sK0, sVt0, skw1, svw1);
        body(2 * k2 + 1, sK1, sVt1, skw0, svw0);
    }

    const int n_img = b / NH_;
    const int head  = b % NH_;
    #pragma unroll
    for (int dt = 0; dt < 2; ++dt) {
        #pragma unroll
        for (int r = 0; r < 16; ++r) {
            const int qloc = (r & 3) + 8 * (r >> 2) + 4 * hi;
            const int qg = qbase + qw + qloc;
            ob[(size_t)(n_img * HW_ + qg) * C_ + head * HD_ + dt * 32 + l31] =
                f2b(Oacc[dt][r] / Osum[r]);
        }
    }
}

extern "C" void kernel_launch(void* const* d_in, const int* in_sizes, int n_in,
                              void* d_out, int out_size, void* d_ws, size_t ws_size,
                              hipStream_t stream) {
    const float* x      = (const float*)d_in[0];
    const float* w_qkv  = (const float*)d_in[1];
    const float* b_qkv  = (const float*)d_in[2];
    const float* w_proj = (const float*)d_in[3];
    const float* b_proj = (const float*)d_in[4];
    const float* rel_h  = (const float*)d_in[5];
    const float* rel_w  = (const float*)d_in[6];
    float* out = (float*)d_out;

    const size_t seg = (size_t)B_ * HW_ * HD_;   // 6,291,456
    char* p = (char*)d_ws;
    u16* xb     = (u16*)p;  p += seg * 2;
    u16* wqkvT  = (u16*)p;  p += (size_t)C3_ * C_ * 2;
    u16* wprojT = (u16*)p;  p += (size_t)C_ * C_ * 2;
    u16* qb     = (u16*)p;  p += seg * 2;
    u16* kbf    = (u16*)p;  p += seg * 2;
    u16* vtb    = (u16*)p;  p += seg * 2;
    u16* ob     = (u16*)p;  p += seg * 2;
    u16* Fg     = (u16*)p;  p += seg * 2;
    u16* Eg     = (u16*)p;  p += seg * 2;

    prep_fused<<<2624, 256, 0, stream>>>(x, xb, w_qkv, wqkvT, w_proj, wprojT);
    gemm_qkv<<<1152, 256, 49152, stream>>>(xb, wqkvT, b_qkv, qb, kbf, vtb);
    ef_gemm<<<768, 256, 0, stream>>>(qb, rel_h, rel_w, Fg, Eg);
    attn_mfma<<<768, 256, 45568, stream>>>(qb, kbf, vtb, Fg, Eg, ob);
    gemm_proj<<<384, 256, 49152, stream>>>(ob, wprojT, b_proj, out);
}